// Round 1
// baseline (1654.699 us; speedup 1.0000x reference)
//
#include <hip/hip_runtime.h>

#define N_ROWS 32768
#define DK 512
#define NC_MAIN 1024
#define NC_S1 512
#define NC_S2 256
#define NCB 1792  // 1024 + 512 + 256

// d_out layout (floats, concatenated reference outputs)
#define MAIN_OFF 0
#define SUB_OFF  16777216
#define LOSS_OFF 33554432
#define MSK_OFF  33554433
#define UNIQ_OFF 33562625

// ---------------------------------------------------------------------------
// init: zero the small accumulators in ws (ws is poisoned 0xAA every launch)
__global__ void init_kernel(int* __restrict__ used, float* __restrict__ loss) {
    int tid = threadIdx.x + blockIdx.x * blockDim.x;
    if (tid < 1024) used[tid] = 0;
    if (tid < 2) loss[tid] = 0.f;
}

// ---------------------------------------------------------------------------
// Build combined codebook CB[1792][512]:
//   rows 0..1023   : copy of c
//   rows 1024..1535: W1 @ c + b1
//   rows 1536..1791: W2 @ c + b2
// block = 256 threads viewed as (64 cols, 4 row-threads); each thread does 4 rows
// grid = (512/64, 1792/16)
__global__ __launch_bounds__(256) void build_subcb(
    const float* __restrict__ c, const float* __restrict__ W1,
    const float* __restrict__ b1, const float* __restrict__ W2,
    const float* __restrict__ b2, float* __restrict__ CB)
{
    int tid = threadIdx.x;
    int tx = tid & 63, ty = tid >> 6;
    int col = blockIdx.x * 64 + tx;
    int row0 = blockIdx.y * 16 + ty * 4;
    if (row0 < 1024) {
#pragma unroll
        for (int r = 0; r < 4; ++r)
            CB[(row0 + r) * DK + col] = c[(row0 + r) * DK + col];
    } else {
        int i0 = row0 - 1024;
        const float* W;
        const float* b;
        if (i0 < 512) { W = W1; b = b1; }
        else          { W = W2; b = b2; i0 -= 512; }
        float acc[4] = {0.f, 0.f, 0.f, 0.f};
        for (int j = 0; j < 1024; ++j) {
            float cv = c[j * DK + col];
#pragma unroll
            for (int r = 0; r < 4; ++r)
                acc[r] += W[(i0 + r) * 1024 + j] * cv;
        }
#pragma unroll
        for (int r = 0; r < 4; ++r)
            CB[(row0 + r) * DK + col] = acc[r] + b[i0 + r];
    }
}

// ---------------------------------------------------------------------------
// Row squared-norms of CB. One wave per row.
__global__ __launch_bounds__(64) void row_norms(const float* __restrict__ CB,
                                                float* __restrict__ norms) {
    int row = blockIdx.x;
    int lane = threadIdx.x;
    const float4* p = (const float4*)(CB + (size_t)row * DK);
    float s = 0.f;
#pragma unroll
    for (int i = lane; i < 128; i += 64) {
        float4 v = p[i];
        s += v.x * v.x + v.y * v.y + v.z * v.z + v.w * v.w;
    }
#pragma unroll
    for (int off = 32; off; off >>= 1) s += __shfl_down(s, off, 64);
    if (lane == 0) norms[row] = s;
}

// ---------------------------------------------------------------------------
// Hot kernel: for each x row, argmin of (||c||^2 - 2 x.c) over the 3 codebook
// segments of CB. Tile: 64 rows x 64 codes, BK=64, 256 threads, 4x4 micro-tile.
// LDS uses a 16B-granule XOR swizzle so both fragment reads are conflict-free
// ds_read_b128: addr(row,k) = row*64 + ((k/4 ^ ((row>>2)&15))*4 + k%4).
__global__ __launch_bounds__(256) void argmin_kernel(
    const float* __restrict__ x, const float* __restrict__ CB,
    const float* __restrict__ norms, int* __restrict__ zm,
    int* __restrict__ z1, int* __restrict__ z2)
{
    __shared__ float xs[64 * 64];
    __shared__ float cs[64 * 64];
    const int tid = threadIdx.x;
    const int tx = tid & 15;   // code-lane (16)
    const int ty = tid >> 4;   // row-lane (16)
    const int rowBase = blockIdx.x * 64;

    const int segStart[3] = {0, 16, 24};   // in 64-code chunks
    const int segEnd[3]   = {16, 24, 28};

    for (int seg = 0; seg < 3; ++seg) {
        float rmin[4];
        int ridx[4];
#pragma unroll
        for (int r = 0; r < 4; ++r) { rmin[r] = 3.4e38f; ridx[r] = 0x7fffffff; }

        for (int chunk = segStart[seg]; chunk < segEnd[seg]; ++chunk) {
            const int c0 = chunk * 64;
            float acc[4][4];
#pragma unroll
            for (int r = 0; r < 4; ++r)
#pragma unroll
                for (int s = 0; s < 4; ++s) acc[r][s] = 0.f;

            for (int kk = 0; kk < DK; kk += 64) {
                __syncthreads();
                // stage 64x64 of x and CB; 4 float4 per thread each
#pragma unroll
                for (int i = 0; i < 4; ++i) {
                    int f = tid + i * 256;
                    int row = f >> 4;
                    int g = f & 15;
                    int sw = ((g ^ ((row >> 2) & 15)) << 2);
                    float4 v = *(const float4*)(&x[(rowBase + row) * DK + kk + (g << 2)]);
                    *(float4*)(&xs[row * 64 + sw]) = v;
                    float4 w = *(const float4*)(&CB[(c0 + row) * DK + kk + (g << 2)]);
                    *(float4*)(&cs[row * 64 + sw]) = w;
                }
                __syncthreads();
#pragma unroll 4
                for (int kc = 0; kc < 16; ++kc) {
                    float4 xf[4], cf[4];
#pragma unroll
                    for (int r = 0; r < 4; ++r)
                        xf[r] = *(const float4*)(&xs[(ty * 4 + r) * 64 + ((kc ^ ty) << 2)]);
#pragma unroll
                    for (int s = 0; s < 4; ++s)
                        cf[s] = *(const float4*)(&cs[(tx * 4 + s) * 64 + ((kc ^ tx) << 2)]);
#pragma unroll
                    for (int r = 0; r < 4; ++r)
#pragma unroll
                        for (int s = 0; s < 4; ++s)
                            acc[r][s] += xf[r].x * cf[s].x + xf[r].y * cf[s].y
                                       + xf[r].z * cf[s].z + xf[r].w * cf[s].w;
                }
            }
            // scores + argmin reduce across the 16 code-lanes
            float nrm[4];
#pragma unroll
            for (int s = 0; s < 4; ++s) nrm[s] = norms[c0 + tx * 4 + s];
#pragma unroll
            for (int r = 0; r < 4; ++r) {
                float best = 3.4e38f;
                int bidx = 0x7fffffff;
#pragma unroll
                for (int s = 0; s < 4; ++s) {
                    float sc = nrm[s] - 2.0f * acc[r][s];
                    int ci = c0 + tx * 4 + s;
                    if (sc < best) { best = sc; bidx = ci; }
                }
#pragma unroll
                for (int m = 1; m < 16; m <<= 1) {
                    float ov = __shfl_xor(best, m, 64);
                    int oi = __shfl_xor(bidx, m, 64);
                    if (ov < best || (ov == best && oi < bidx)) { best = ov; bidx = oi; }
                }
                if (best < rmin[r] || (best == rmin[r] && bidx < ridx[r])) {
                    rmin[r] = best; ridx[r] = bidx;
                }
            }
        }
        if (tx == 0) {
#pragma unroll
            for (int r = 0; r < 4; ++r) {
                int gr = rowBase + ty * 4 + r;
                if (seg == 0)      zm[gr] = ridx[r];
                else if (seg == 1) z1[gr] = ridx[r] - NC_MAIN;
                else               z2[gr] = ridx[r] - (NC_MAIN + NC_S1);
            }
        }
    }
}

// ---------------------------------------------------------------------------
// Gather codebook rows into outputs, accumulate the two MSE sums, mark used
// main codes. One wave per x row; 4 rows per block.
__global__ __launch_bounds__(256) void gather_kernel(
    const float* __restrict__ x, const float* __restrict__ CB,
    const int* __restrict__ zm, const int* __restrict__ z1,
    const int* __restrict__ z2, float* __restrict__ main_out,
    float* __restrict__ sub_out, float* __restrict__ loss,
    int* __restrict__ used)
{
    int tid = threadIdx.x;
    int lane = tid & 63;
    int wv = tid >> 6;
    int row = blockIdx.x * 4 + wv;
    int a = zm[row];
    int i1 = NC_MAIN + z1[row];
    int i2 = NC_MAIN + NC_S1 + z2[row];
    const float4* xv = (const float4*)(x + (size_t)row * DK);
    const float4* ca = (const float4*)(CB + (size_t)a * DK);
    const float4* c1 = (const float4*)(CB + (size_t)i1 * DK);
    const float4* c2 = (const float4*)(CB + (size_t)i2 * DK);
    float4* mo = (float4*)(main_out + (size_t)row * DK);
    float4* so = (float4*)(sub_out + (size_t)row * DK);
    float em = 0.f, es = 0.f;
#pragma unroll
    for (int i = lane; i < 128; i += 64) {
        float4 xq = xv[i];
        float4 cm = ca[i];
        float4 q1 = c1[i];
        float4 q2 = c2[i];
        float4 csv;
        csv.x = 0.5f * (q1.x + q2.x);
        csv.y = 0.5f * (q1.y + q2.y);
        csv.z = 0.5f * (q1.z + q2.z);
        csv.w = 0.5f * (q1.w + q2.w);
        mo[i] = cm;
        so[i] = csv;
        float d;
        d = cm.x - xq.x; em += d * d;
        d = cm.y - xq.y; em += d * d;
        d = cm.z - xq.z; em += d * d;
        d = cm.w - xq.w; em += d * d;
        d = csv.x - xq.x; es += d * d;
        d = csv.y - xq.y; es += d * d;
        d = csv.z - xq.z; es += d * d;
        d = csv.w - xq.w; es += d * d;
    }
#pragma unroll
    for (int off = 32; off; off >>= 1) {
        em += __shfl_down(em, off, 64);
        es += __shfl_down(es, off, 64);
    }
    __shared__ float sm[8];
    if (lane == 0) { sm[wv] = em; sm[4 + wv] = es; }
    __syncthreads();
    if (tid == 0) {
        atomicAdd(&loss[0], sm[0] + sm[1] + sm[2] + sm[3]);
        atomicAdd(&loss[1], sm[4] + sm[5] + sm[6] + sm[7]);
    }
    if (lane == 0) used[a] = 1;  // benign race: same value
}

// ---------------------------------------------------------------------------
__global__ __launch_bounds__(256) void finalize_kernel(
    const int* __restrict__ used, const float* __restrict__ loss,
    const int* __restrict__ training, float* __restrict__ out)
{
    int tid = threadIdx.x;
    int cnt = 0;
    for (int i = tid; i < 1024; i += 256) cnt += (used[i] != 0);
#pragma unroll
    for (int off = 32; off; off >>= 1) cnt += __shfl_down(cnt, off, 64);
    __shared__ int sc[4];
    if ((tid & 63) == 0) sc[tid >> 6] = cnt;
    __syncthreads();
    if (tid == 0) {
        int total = sc[0] + sc[1] + sc[2] + sc[3];
        float tl = 0.f;
        if (*training)
            tl = 1.25f * (loss[0] + loss[1]) * (1.0f / ((float)N_ROWS * (float)DK));
        out[LOSS_OFF] = tl;
        out[UNIQ_OFF] = (float)total;
    }
    for (int i = tid; i < 8192; i += 256) out[MSK_OFF + i] = 0.f;
}

// ---------------------------------------------------------------------------
extern "C" void kernel_launch(void* const* d_in, const int* in_sizes, int n_in,
                              void* d_out, int out_size, void* d_ws, size_t ws_size,
                              hipStream_t stream) {
    const float* x = (const float*)d_in[0];
    const float* c = (const float*)d_in[1];
    const float* W1 = (const float*)d_in[2];
    const float* b1 = (const float*)d_in[3];
    const float* W2 = (const float*)d_in[4];
    const float* b2 = (const float*)d_in[5];
    const int* training = (const int*)d_in[6];
    float* out = (float*)d_out;

    // ws layout
    float* CB = (float*)d_ws;                 // 1792*512 f32
    float* norms = CB + (size_t)NCB * DK;     // 1792 f32
    int* zm = (int*)(norms + NCB);            // 32768 i32
    int* z1v = zm + N_ROWS;                   // 32768 i32
    int* z2v = z1v + N_ROWS;                  // 32768 i32
    int* used = z2v + N_ROWS;                 // 1024 i32
    float* loss = (float*)(used + 1024);      // 2 f32

    init_kernel<<<dim3(4), dim3(256), 0, stream>>>(used, loss);
    build_subcb<<<dim3(8, 112), dim3(256), 0, stream>>>(c, W1, b1, W2, b2, CB);
    row_norms<<<dim3(NCB), dim3(64), 0, stream>>>(CB, norms);
    argmin_kernel<<<dim3(512), dim3(256), 0, stream>>>(x, CB, norms, zm, z1v, z2v);
    gather_kernel<<<dim3(8192), dim3(256), 0, stream>>>(
        x, CB, zm, z1v, z2v, out + MAIN_OFF, out + SUB_OFF, loss, used);
    finalize_kernel<<<dim3(1), dim3(256), 0, stream>>>(used, loss, training, out);
}

// Round 2
// 1229.631 us; speedup vs baseline: 1.3457x; 1.3457x over previous
//
#include <hip/hip_runtime.h>
#include <cstdint>

typedef unsigned short ushort_t;
typedef unsigned int uint_t;
typedef _Float16 f16x8 __attribute__((ext_vector_type(8)));
typedef float f32x4 __attribute__((ext_vector_type(4)));

#define N_ROWS 32768
#define DK 512
#define NC_MAIN 1024
#define NCB 1792  // 1024 + 512 + 256
#define NTILE 14  // 1792 / 128

// d_out layout (floats, concatenated reference outputs)
#define MAIN_OFF 0
#define SUB_OFF  16777216
#define LOSS_OFF 33554432
#define MSK_OFF  33554433
#define UNIQ_OFF 33562625

// ---------------------------------------------------------------------------
__global__ void init_kernel(int* __restrict__ used, float* __restrict__ loss) {
    int tid = threadIdx.x + blockIdx.x * blockDim.x;
    if (tid < 1024) used[tid] = 0;
    if (tid < 2) loss[tid] = 0.f;
}

// ---------------------------------------------------------------------------
// Build combined codebook CB[1792][512] (fp32): rows 0..1023 copy of c;
// 1024..1535 = W1@c+b1; 1536..1791 = W2@c+b2.
__global__ __launch_bounds__(256) void build_subcb(
    const float* __restrict__ c, const float* __restrict__ W1,
    const float* __restrict__ b1, const float* __restrict__ W2,
    const float* __restrict__ b2, float* __restrict__ CB)
{
    int tid = threadIdx.x;
    int tx = tid & 63, ty = tid >> 6;
    int col = blockIdx.x * 64 + tx;
    int row0 = blockIdx.y * 16 + ty * 4;
    if (row0 < 1024) {
#pragma unroll
        for (int r = 0; r < 4; ++r)
            CB[(row0 + r) * DK + col] = c[(row0 + r) * DK + col];
    } else {
        int i0 = row0 - 1024;
        const float* W;
        const float* b;
        if (i0 < 512) { W = W1; b = b1; }
        else          { W = W2; b = b2; i0 -= 512; }
        float acc[4] = {0.f, 0.f, 0.f, 0.f};
        for (int j = 0; j < 1024; ++j) {
            float cv = c[j * DK + col];
#pragma unroll
            for (int r = 0; r < 4; ++r)
                acc[r] += W[(i0 + r) * 1024 + j] * cv;
        }
#pragma unroll
        for (int r = 0; r < 4; ++r)
            CB[(row0 + r) * DK + col] = acc[r] + b[i0 + r];
    }
}

// ---------------------------------------------------------------------------
__global__ __launch_bounds__(64) void row_norms(const float* __restrict__ CB,
                                                float* __restrict__ norms) {
    int row = blockIdx.x;
    int lane = threadIdx.x;
    const float4* p = (const float4*)(CB + (size_t)row * DK);
    float s = 0.f;
#pragma unroll
    for (int i = lane; i < 128; i += 64) {
        float4 v = p[i];
        s += v.x * v.x + v.y * v.y + v.z * v.z + v.w * v.w;
    }
#pragma unroll
    for (int off = 32; off; off >>= 1) s += __shfl_down(s, off, 64);
    if (lane == 0) norms[row] = s;
}

// ---------------------------------------------------------------------------
// fp32 -> f16 (RN), 8 elems/thread
__global__ __launch_bounds__(256) void cvt_f16(const float* __restrict__ in,
                                               _Float16* __restrict__ out, int n8) {
    int i = blockIdx.x * 256 + threadIdx.x;
    if (i >= n8) return;
    const float4* p = (const float4*)in + (size_t)i * 2;
    float4 a = p[0], b = p[1];
    f16x8 o;
    o[0] = (_Float16)a.x; o[1] = (_Float16)a.y; o[2] = (_Float16)a.z; o[3] = (_Float16)a.w;
    o[4] = (_Float16)b.x; o[5] = (_Float16)b.y; o[6] = (_Float16)b.z; o[7] = (_Float16)b.w;
    *((f16x8*)out + i) = o;
}

// ---------------------------------------------------------------------------
__device__ __forceinline__ void async16(void* lds, const void* g) {
    __builtin_amdgcn_global_load_lds(
        (const __attribute__((address_space(1))) unsigned int*)(uintptr_t)g,
        (__attribute__((address_space(3))) unsigned int*)(uintptr_t)lds,
        16, 0, 0);
}

__device__ __forceinline__ float dec_key(uint_t key) {
    uint_t u = key & 0xFFFFFF80u;
    uint_t bits = (u & 0x80000000u) ? (u ^ 0x80000000u) : ~u;
    return __uint_as_float(bits);
}

// ---------------------------------------------------------------------------
// MFMA f16 GEMM S = xh . cbh^T with per-(row, 128-col-tile) top-2 epilogue.
// Block: 256 thr = 4 waves (2x2), tile 128x128, BK=64.
// LDS layout is lane-linear (global_load_lds constraint); bank-conflict
// avoidance is done by XOR-permuting which GLOBAL granule each lane fetches:
// LDS[row][g'] holds global granule (row, g'^(row&7)).
__global__ __launch_bounds__(256) void gemm_topk(
    const _Float16* __restrict__ xh, const _Float16* __restrict__ cbh,
    const float* __restrict__ norms, float4* __restrict__ candbuf)
{
    __shared__ __align__(16) ushort_t As[128 * 64];
    __shared__ __align__(16) ushort_t Bs[128 * 64];
    __shared__ uint2 cand[128][2];

    const int tid = threadIdx.x;
    const int lane = tid & 63;
    const int wid = tid >> 6;
    const int wy = wid >> 1, wx = wid & 1;
    const int lane15 = lane & 15, q = lane >> 4;

    const int tileN = blockIdx.x;       // 0..13
    const int rowBase = blockIdx.y * 128;
    const int c0 = tileN * 128;

    // staging offsets (element units)
    size_t aoff[4], boff[4];
    int ldsoff[4];
#pragma unroll
    for (int i = 0; i < 4; ++i) {
        int gid = i * 256 + tid;
        int row = gid >> 3;
        int gp = gid & 7;
        int gsw = gp ^ (row & 7);
        aoff[i] = (size_t)(rowBase + row) * DK + gsw * 8;
        boff[i] = (size_t)(c0 + row) * DK + gsw * 8;
        ldsoff[i] = gid * 8;
    }

    // fragment LDS row bases
    int rA[4], rB[4];
#pragma unroll
    for (int t = 0; t < 4; ++t) {
        rA[t] = wy * 64 + t * 16 + lane15;
        rB[t] = wx * 64 + t * 16 + lane15;
    }

    f32x4 acc[4][4];
#pragma unroll
    for (int mr = 0; mr < 4; ++mr)
#pragma unroll
        for (int nc = 0; nc < 4; ++nc) acc[mr][nc] = (f32x4)0.f;

    for (int kk = 0; kk < DK; kk += 64) {
        __syncthreads();
#pragma unroll
        for (int i = 0; i < 4; ++i) async16(&As[ldsoff[i]], xh + aoff[i] + kk);
#pragma unroll
        for (int i = 0; i < 4; ++i) async16(&Bs[ldsoff[i]], cbh + boff[i] + kk);
        __syncthreads();
#pragma unroll
        for (int chunk = 0; chunk < 2; ++chunk) {
            f16x8 av[4], bv[4];
            int kg = (chunk << 2) | q;
#pragma unroll
            for (int mr = 0; mr < 4; ++mr)
                av[mr] = *(const f16x8*)&As[rA[mr] * 64 + (kg ^ (rA[mr] & 7)) * 8];
#pragma unroll
            for (int nc = 0; nc < 4; ++nc)
                bv[nc] = *(const f16x8*)&Bs[rB[nc] * 64 + (kg ^ (rB[nc] & 7)) * 8];
#pragma unroll
            for (int mr = 0; mr < 4; ++mr)
#pragma unroll
                for (int nc = 0; nc < 4; ++nc)
                    acc[mr][nc] = __builtin_amdgcn_mfma_f32_16x16x32_f16(
                        av[mr], bv[nc], acc[mr][nc], 0, 0, 0);
        }
    }

    // ---------------- epilogue: per-row top-2 over the 128-col tile ----------
    float nrm[4];
    uint_t colLoc[4];
#pragma unroll
    for (int nc = 0; nc < 4; ++nc) {
        colLoc[nc] = (uint_t)(wx * 64 + nc * 16 + lane15);
        nrm[nc] = norms[c0 + (int)colLoc[nc]];
    }

#pragma unroll
    for (int mr = 0; mr < 4; ++mr) {
#pragma unroll
        for (int r = 0; r < 4; ++r) {
            uint_t k[4];
#pragma unroll
            for (int nc = 0; nc < 4; ++nc) {
                float s = fmaf(-2.f, acc[mr][nc][r], nrm[nc]);
                uint_t b = __float_as_uint(s);
                uint_t u = b ^ ((uint_t)((int)b >> 31) | 0x80000000u);
                k[nc] = (u & 0xFFFFFF80u) | colLoc[nc];
            }
            uint_t lo01 = min(k[0], k[1]), hi01 = max(k[0], k[1]);
            uint_t lo23 = min(k[2], k[3]), hi23 = max(k[2], k[3]);
            uint_t k1 = min(lo01, lo23);
            uint_t k2 = min(min(hi01, hi23), max(lo01, lo23));
#pragma unroll
            for (int m = 1; m <= 8; m <<= 1) {
                uint_t o1 = __shfl_xor(k1, m, 64);
                uint_t o2 = __shfl_xor(k2, m, 64);
                uint_t n1 = min(k1, o1);
                uint_t n2 = min(max(k1, o1), min(k2, o2));
                k1 = n1; k2 = n2;
            }
            if (lane15 == 0) {
                int rloc = wy * 64 + mr * 16 + q * 4 + r;
                cand[rloc][wx] = make_uint2(k1, k2);
            }
        }
    }
    __syncthreads();
    if (tid < 128) {
        uint2 a = cand[tid][0], b = cand[tid][1];
        uint_t k1 = min(a.x, b.x);
        uint_t k2 = min(max(a.x, b.x), min(a.y, b.y));
        float s1 = dec_key(k1), s2 = dec_key(k2);
        int i1 = c0 + (int)(k1 & 127u);
        int i2 = c0 + (int)(k2 & 127u);
        float4 e;
        e.x = s1; e.y = __int_as_float(i1);
        e.z = s2; e.w = __int_as_float(i2);
        candbuf[(size_t)(rowBase + tid) * NTILE + tileN] = e;
    }
}

// ---------------------------------------------------------------------------
// Per x-row: merge tile candidates per segment (top-4 by approx score),
// rescore exactly in fp32, pick argmin (tie -> lowest idx), then gather rows,
// write outputs, accumulate loss, mark used. One wave per row.
__device__ __forceinline__ void push4(float v, int idx, float* bs, int* bi) {
#pragma unroll
    for (int j = 0; j < 4; ++j) {
        bool lt = (v < bs[j]) || (v == bs[j] && idx < bi[j]);
        if (lt) { float tv = bs[j]; int ti = bi[j]; bs[j] = v; bi[j] = idx; v = tv; idx = ti; }
    }
}

__global__ __launch_bounds__(256) void rescue_gather(
    const float* __restrict__ x, const float* __restrict__ CB,
    const float* __restrict__ norms, const float4* __restrict__ candbuf,
    float* __restrict__ main_out, float* __restrict__ sub_out,
    float* __restrict__ loss, int* __restrict__ used)
{
    const int lane = threadIdx.x & 63;
    const int r = blockIdx.x * 4 + (threadIdx.x >> 6);

    const float4* xp = (const float4*)(x + (size_t)r * DK) + lane * 2;
    float4 xa = xp[0], xb = xp[1];

    const float4* cbp = candbuf + (size_t)r * NTILE;

    float sv[12];
    int si[12];
    {
        float bs[4]; int bi[4];
        // main: tiles 0..7
#pragma unroll
        for (int j = 0; j < 4; ++j) { bs[j] = 3.4e38f; bi[j] = 0x7fffffff; }
#pragma unroll
        for (int t = 0; t < 8; ++t) {
            float4 e = cbp[t];
            push4(e.x, __float_as_int(e.y), bs, bi);
            push4(e.z, __float_as_int(e.w), bs, bi);
        }
#pragma unroll
        for (int j = 0; j < 4; ++j) { sv[j] = bs[j]; si[j] = bi[j]; }
        // s1: tiles 8..11
#pragma unroll
        for (int j = 0; j < 4; ++j) { bs[j] = 3.4e38f; bi[j] = 0x7fffffff; }
#pragma unroll
        for (int t = 8; t < 12; ++t) {
            float4 e = cbp[t];
            push4(e.x, __float_as_int(e.y), bs, bi);
            push4(e.z, __float_as_int(e.w), bs, bi);
        }
#pragma unroll
        for (int j = 0; j < 4; ++j) { sv[4 + j] = bs[j]; si[4 + j] = bi[j]; }
        // s2: tiles 12..13 (4 candidates total)
#pragma unroll
        for (int j = 0; j < 4; ++j) { bs[j] = 3.4e38f; bi[j] = 0x7fffffff; }
#pragma unroll
        for (int t = 12; t < 14; ++t) {
            float4 e = cbp[t];
            push4(e.x, __float_as_int(e.y), bs, bi);
            push4(e.z, __float_as_int(e.w), bs, bi);
        }
#pragma unroll
        for (int j = 0; j < 4; ++j) { sv[8 + j] = bs[j]; si[8 + j] = bi[j]; }
    }

    // exact fp32 dots for all 12 candidates
    float d[12];
#pragma unroll
    for (int k = 0; k < 12; ++k) {
        const float4* cp = (const float4*)(CB + (size_t)si[k] * DK) + lane * 2;
        float4 a = cp[0], b = cp[1];
        d[k] = xa.x * a.x + xa.y * a.y + xa.z * a.z + xa.w * a.w
             + xb.x * b.x + xb.y * b.y + xb.z * b.z + xb.w * b.w;
    }
#pragma unroll
    for (int off = 32; off; off >>= 1)
#pragma unroll
        for (int k = 0; k < 12; ++k) d[k] += __shfl_xor(d[k], off, 64);

    float sc[12];
#pragma unroll
    for (int k = 0; k < 12; ++k) sc[k] = norms[si[k]] - 2.f * d[k];

    int pick[3];
#pragma unroll
    for (int g = 0; g < 3; ++g) {
        float bv = sc[g * 4]; int bidx = si[g * 4];
#pragma unroll
        for (int k = 1; k < 4; ++k) {
            float v = sc[g * 4 + k]; int idx = si[g * 4 + k];
            if (v < bv || (v == bv && idx < bidx)) { bv = v; bidx = idx; }
        }
        pick[g] = bidx;
    }
    const int A = pick[0], B = pick[1], C = pick[2];

    // gather + write + loss
    const float4* pa = (const float4*)(CB + (size_t)A * DK) + lane * 2;
    const float4* pb = (const float4*)(CB + (size_t)B * DK) + lane * 2;
    const float4* pc = (const float4*)(CB + (size_t)C * DK) + lane * 2;
    float4* mo = (float4*)(main_out + (size_t)r * DK) + lane * 2;
    float4* so = (float4*)(sub_out + (size_t)r * DK) + lane * 2;
    float em = 0.f, es = 0.f;
#pragma unroll
    for (int i = 0; i < 2; ++i) {
        float4 xq = (i == 0) ? xa : xb;
        float4 cm = pa[i];
        float4 q1 = pb[i];
        float4 q2 = pc[i];
        float4 cs;
        cs.x = 0.5f * (q1.x + q2.x);
        cs.y = 0.5f * (q1.y + q2.y);
        cs.z = 0.5f * (q1.z + q2.z);
        cs.w = 0.5f * (q1.w + q2.w);
        mo[i] = cm;
        so[i] = cs;
        float t;
        t = cm.x - xq.x; em += t * t;
        t = cm.y - xq.y; em += t * t;
        t = cm.z - xq.z; em += t * t;
        t = cm.w - xq.w; em += t * t;
        t = cs.x - xq.x; es += t * t;
        t = cs.y - xq.y; es += t * t;
        t = cs.z - xq.z; es += t * t;
        t = cs.w - xq.w; es += t * t;
    }
#pragma unroll
    for (int off = 32; off; off >>= 1) {
        em += __shfl_down(em, off, 64);
        es += __shfl_down(es, off, 64);
    }
    if (lane == 0) {
        atomicAdd(&loss[0], em);
        atomicAdd(&loss[1], es);
        used[A] = 1;
    }
}

// ---------------------------------------------------------------------------
__global__ __launch_bounds__(256) void finalize_kernel(
    const int* __restrict__ used, const float* __restrict__ loss,
    const int* __restrict__ training, float* __restrict__ out)
{
    int tid = threadIdx.x;
    int cnt = 0;
    for (int i = tid; i < 1024; i += 256) cnt += (used[i] != 0);
#pragma unroll
    for (int off = 32; off; off >>= 1) cnt += __shfl_down(cnt, off, 64);
    __shared__ int sc[4];
    if ((tid & 63) == 0) sc[tid >> 6] = cnt;
    __syncthreads();
    if (tid == 0) {
        int total = sc[0] + sc[1] + sc[2] + sc[3];
        float tl = 0.f;
        if (*training)
            tl = 1.25f * (loss[0] + loss[1]) * (1.0f / ((float)N_ROWS * (float)DK));
        out[LOSS_OFF] = tl;
        out[UNIQ_OFF] = (float)total;
    }
    for (int i = tid; i < 8192; i += 256) out[MSK_OFF + i] = 0.f;
}

// ---------------------------------------------------------------------------
extern "C" void kernel_launch(void* const* d_in, const int* in_sizes, int n_in,
                              void* d_out, int out_size, void* d_ws, size_t ws_size,
                              hipStream_t stream) {
    const float* x = (const float*)d_in[0];
    const float* c = (const float*)d_in[1];
    const float* W1 = (const float*)d_in[2];
    const float* b1 = (const float*)d_in[3];
    const float* W2 = (const float*)d_in[4];
    const float* b2 = (const float*)d_in[5];
    const int* training = (const int*)d_in[6];
    float* out = (float*)d_out;

    // ws layout (all offsets 16B aligned); total ~46.4 MB
    char* p = (char*)d_ws;
    float* CB = (float*)p;          p += (size_t)NCB * DK * 4;      // 3,670,016
    _Float16* xh = (_Float16*)p;    p += (size_t)N_ROWS * DK * 2;   // 33,554,432
    _Float16* cbh = (_Float16*)p;   p += (size_t)NCB * DK * 2;      // 1,835,008
    float4* candbuf = (float4*)p;   p += (size_t)N_ROWS * NTILE * 16; // 7,340,032
    float* norms = (float*)p;       p += NCB * 4;                   // 7,168
    int* used = (int*)p;            p += 4096;
    float* loss = (float*)p;

    init_kernel<<<dim3(4), dim3(256), 0, stream>>>(used, loss);
    build_subcb<<<dim3(8, 112), dim3(256), 0, stream>>>(c, W1, b1, W2, b2, CB);
    row_norms<<<dim3(NCB), dim3(64), 0, stream>>>(CB, norms);
    cvt_f16<<<dim3(8192), dim3(256), 0, stream>>>(x, xh, N_ROWS * DK / 8);
    cvt_f16<<<dim3(448), dim3(256), 0, stream>>>(CB, cbh, NCB * DK / 8);
    gemm_topk<<<dim3(NTILE, 256), dim3(256), 0, stream>>>(xh, cbh, norms, candbuf);
    rescue_gather<<<dim3(8192), dim3(256), 0, stream>>>(
        x, CB, norms, candbuf, out + MAIN_OFF, out + SUB_OFF, loss, used);
    finalize_kernel<<<dim3(1), dim3(256), 0, stream>>>(used, loss, training, out);
}

// Round 3
// 476.169 us; speedup vs baseline: 3.4750x; 2.5823x over previous
//
#include <hip/hip_runtime.h>
#include <cstdint>

typedef unsigned short ushort_t;
typedef unsigned int uint_t;
typedef _Float16 f16x8 __attribute__((ext_vector_type(8)));
typedef float f32x4 __attribute__((ext_vector_type(4)));

#define N_ROWS 32768
#define DK 512
#define NC_MAIN 1024
#define NCB 1792  // 1024 + 512 + 256
#define NTILE 14  // 1792 / 128
#define NBLK_RG 8192  // rescue_gather blocks (4 rows each)

// d_out layout (floats, concatenated reference outputs)
#define MAIN_OFF 0
#define SUB_OFF  16777216
#define LOSS_OFF 33554432
#define MSK_OFF  33554433
#define UNIQ_OFF 33562625

// ---------------------------------------------------------------------------
__global__ void init_kernel(int* __restrict__ used) {
    int tid = threadIdx.x + blockIdx.x * blockDim.x;
    if (tid < 1024) used[tid] = 0;
}

// ---------------------------------------------------------------------------
// Build combined codebook CB[1792][512] (fp32): rows 0..1023 copy of c;
// 1024..1535 = W1@c+b1; 1536..1791 = W2@c+b2.
__global__ __launch_bounds__(256) void build_subcb(
    const float* __restrict__ c, const float* __restrict__ W1,
    const float* __restrict__ b1, const float* __restrict__ W2,
    const float* __restrict__ b2, float* __restrict__ CB)
{
    int tid = threadIdx.x;
    int tx = tid & 63, ty = tid >> 6;
    int col = blockIdx.x * 64 + tx;
    int row0 = blockIdx.y * 16 + ty * 4;
    if (row0 < 1024) {
#pragma unroll
        for (int r = 0; r < 4; ++r)
            CB[(row0 + r) * DK + col] = c[(row0 + r) * DK + col];
    } else {
        int i0 = row0 - 1024;
        const float* W;
        const float* b;
        if (i0 < 512) { W = W1; b = b1; }
        else          { W = W2; b = b2; i0 -= 512; }
        float acc[4] = {0.f, 0.f, 0.f, 0.f};
        for (int j = 0; j < 1024; ++j) {
            float cv = c[j * DK + col];
#pragma unroll
            for (int r = 0; r < 4; ++r)
                acc[r] += W[(i0 + r) * 1024 + j] * cv;
        }
#pragma unroll
        for (int r = 0; r < 4; ++r)
            CB[(row0 + r) * DK + col] = acc[r] + b[i0 + r];
    }
}

// ---------------------------------------------------------------------------
__global__ __launch_bounds__(64) void row_norms(const float* __restrict__ CB,
                                                float* __restrict__ norms) {
    int row = blockIdx.x;
    int lane = threadIdx.x;
    const float4* p = (const float4*)(CB + (size_t)row * DK);
    float s = 0.f;
#pragma unroll
    for (int i = lane; i < 128; i += 64) {
        float4 v = p[i];
        s += v.x * v.x + v.y * v.y + v.z * v.z + v.w * v.w;
    }
#pragma unroll
    for (int off = 32; off; off >>= 1) s += __shfl_down(s, off, 64);
    if (lane == 0) norms[row] = s;
}

// ---------------------------------------------------------------------------
// fp32 -> f16 (RN), 8 elems/thread
__global__ __launch_bounds__(256) void cvt_f16(const float* __restrict__ in,
                                               _Float16* __restrict__ out, int n8) {
    int i = blockIdx.x * 256 + threadIdx.x;
    if (i >= n8) return;
    const float4* p = (const float4*)in + (size_t)i * 2;
    float4 a = p[0], b = p[1];
    f16x8 o;
    o[0] = (_Float16)a.x; o[1] = (_Float16)a.y; o[2] = (_Float16)a.z; o[3] = (_Float16)a.w;
    o[4] = (_Float16)b.x; o[5] = (_Float16)b.y; o[6] = (_Float16)b.z; o[7] = (_Float16)b.w;
    *((f16x8*)out + i) = o;
}

// ---------------------------------------------------------------------------
__device__ __forceinline__ void async16(void* lds, const void* g) {
    __builtin_amdgcn_global_load_lds(
        (const __attribute__((address_space(1))) unsigned int*)(uintptr_t)g,
        (__attribute__((address_space(3))) unsigned int*)(uintptr_t)lds,
        16, 0, 0);
}

__device__ __forceinline__ float dec_key(uint_t key) {
    uint_t u = key & 0xFFFFFF80u;
    uint_t bits = (u & 0x80000000u) ? (u ^ 0x80000000u) : ~u;
    return __uint_as_float(bits);
}

// ---------------------------------------------------------------------------
// MFMA f16 GEMM S = xh . cbh^T with per-(row, 128-col-tile) top-2 epilogue.
// Block: 256 thr = 4 waves (2x2), tile 128x128, BK=64.
// LDS layout is lane-linear (global_load_lds constraint); bank-conflict
// avoidance via XOR-permuting which GLOBAL granule each lane fetches:
// LDS[row][g'] holds global granule (row, g'^(row&7)).
__global__ __launch_bounds__(256) void gemm_topk(
    const _Float16* __restrict__ xh, const _Float16* __restrict__ cbh,
    const float* __restrict__ norms, float4* __restrict__ candbuf)
{
    __shared__ __align__(16) ushort_t As[128 * 64];
    __shared__ __align__(16) ushort_t Bs[128 * 64];
    __shared__ uint2 cand[128][2];

    const int tid = threadIdx.x;
    const int lane = tid & 63;
    const int wid = tid >> 6;
    const int wy = wid >> 1, wx = wid & 1;
    const int lane15 = lane & 15, q = lane >> 4;

    const int tileN = blockIdx.x;       // 0..13
    const int rowBase = blockIdx.y * 128;
    const int c0 = tileN * 128;

    // staging offsets (element units)
    size_t aoff[4], boff[4];
    int ldsoff[4];
#pragma unroll
    for (int i = 0; i < 4; ++i) {
        int gid = i * 256 + tid;
        int row = gid >> 3;
        int gp = gid & 7;
        int gsw = gp ^ (row & 7);
        aoff[i] = (size_t)(rowBase + row) * DK + gsw * 8;
        boff[i] = (size_t)(c0 + row) * DK + gsw * 8;
        ldsoff[i] = gid * 8;
    }

    // fragment LDS row bases
    int rA[4], rB[4];
#pragma unroll
    for (int t = 0; t < 4; ++t) {
        rA[t] = wy * 64 + t * 16 + lane15;
        rB[t] = wx * 64 + t * 16 + lane15;
    }

    f32x4 acc[4][4];
#pragma unroll
    for (int mr = 0; mr < 4; ++mr)
#pragma unroll
        for (int nc = 0; nc < 4; ++nc) acc[mr][nc] = (f32x4)0.f;

    for (int kk = 0; kk < DK; kk += 64) {
        __syncthreads();
#pragma unroll
        for (int i = 0; i < 4; ++i) async16(&As[ldsoff[i]], xh + aoff[i] + kk);
#pragma unroll
        for (int i = 0; i < 4; ++i) async16(&Bs[ldsoff[i]], cbh + boff[i] + kk);
        __syncthreads();
#pragma unroll
        for (int chunk = 0; chunk < 2; ++chunk) {
            f16x8 av[4], bv[4];
            int kg = (chunk << 2) | q;
#pragma unroll
            for (int mr = 0; mr < 4; ++mr)
                av[mr] = *(const f16x8*)&As[rA[mr] * 64 + (kg ^ (rA[mr] & 7)) * 8];
#pragma unroll
            for (int nc = 0; nc < 4; ++nc)
                bv[nc] = *(const f16x8*)&Bs[rB[nc] * 64 + (kg ^ (rB[nc] & 7)) * 8];
#pragma unroll
            for (int mr = 0; mr < 4; ++mr)
#pragma unroll
                for (int nc = 0; nc < 4; ++nc)
                    acc[mr][nc] = __builtin_amdgcn_mfma_f32_16x16x32_f16(
                        av[mr], bv[nc], acc[mr][nc], 0, 0, 0);
        }
    }

    // ---------------- epilogue: per-row top-2 over the 128-col tile ----------
    float nrm[4];
    uint_t colLoc[4];
#pragma unroll
    for (int nc = 0; nc < 4; ++nc) {
        colLoc[nc] = (uint_t)(wx * 64 + nc * 16 + lane15);
        nrm[nc] = norms[c0 + (int)colLoc[nc]];
    }

#pragma unroll
    for (int mr = 0; mr < 4; ++mr) {
#pragma unroll
        for (int r = 0; r < 4; ++r) {
            uint_t k[4];
#pragma unroll
            for (int nc = 0; nc < 4; ++nc) {
                float s = fmaf(-2.f, acc[mr][nc][r], nrm[nc]);
                uint_t b = __float_as_uint(s);
                uint_t u = b ^ ((uint_t)((int)b >> 31) | 0x80000000u);
                k[nc] = (u & 0xFFFFFF80u) | colLoc[nc];
            }
            uint_t lo01 = min(k[0], k[1]), hi01 = max(k[0], k[1]);
            uint_t lo23 = min(k[2], k[3]), hi23 = max(k[2], k[3]);
            uint_t k1 = min(lo01, lo23);
            uint_t k2 = min(min(hi01, hi23), max(lo01, lo23));
#pragma unroll
            for (int m = 1; m <= 8; m <<= 1) {
                uint_t o1 = __shfl_xor(k1, m, 64);
                uint_t o2 = __shfl_xor(k2, m, 64);
                uint_t n1 = min(k1, o1);
                uint_t n2 = min(max(k1, o1), min(k2, o2));
                k1 = n1; k2 = n2;
            }
            if (lane15 == 0) {
                int rloc = wy * 64 + mr * 16 + q * 4 + r;
                cand[rloc][wx] = make_uint2(k1, k2);
            }
        }
    }
    __syncthreads();
    if (tid < 128) {
        uint2 a = cand[tid][0], b = cand[tid][1];
        uint_t k1 = min(a.x, b.x);
        uint_t k2 = min(max(a.x, b.x), min(a.y, b.y));
        float s1 = dec_key(k1), s2 = dec_key(k2);
        int i1 = c0 + (int)(k1 & 127u);
        int i2 = c0 + (int)(k2 & 127u);
        float4 e;
        e.x = s1; e.y = __int_as_float(i1);
        e.z = s2; e.w = __int_as_float(i2);
        candbuf[(size_t)(rowBase + tid) * NTILE + tileN] = e;
    }
}

// ---------------------------------------------------------------------------
// Per x-row: merge tile candidates per segment (top-4 by approx score),
// rescore exactly in fp32, pick argmin (tie -> lowest idx), then gather rows,
// write outputs, accumulate loss partials (NO global atomics — one float2
// partial per block, reduced in finalize), mark used. One wave per row.
__device__ __forceinline__ void push4(float v, int idx, float* bs, int* bi) {
#pragma unroll
    for (int j = 0; j < 4; ++j) {
        bool lt = (v < bs[j]) || (v == bs[j] && idx < bi[j]);
        if (lt) { float tv = bs[j]; int ti = bi[j]; bs[j] = v; bi[j] = idx; v = tv; idx = ti; }
    }
}

__global__ __launch_bounds__(256) void rescue_gather(
    const float* __restrict__ x, const float* __restrict__ CB,
    const float* __restrict__ norms, const float4* __restrict__ candbuf,
    float* __restrict__ main_out, float* __restrict__ sub_out,
    float2* __restrict__ lossPart, int* __restrict__ used)
{
    const int lane = threadIdx.x & 63;
    const int wv = threadIdx.x >> 6;
    const int r = blockIdx.x * 4 + wv;

    const float4* xp = (const float4*)(x + (size_t)r * DK) + lane * 2;
    float4 xa = xp[0], xb = xp[1];

    const float4* cbp = candbuf + (size_t)r * NTILE;

    int si[12];
    {
        float bs[4]; int bi[4];
        // main: tiles 0..7
#pragma unroll
        for (int j = 0; j < 4; ++j) { bs[j] = 3.4e38f; bi[j] = 0x7fffffff; }
#pragma unroll
        for (int t = 0; t < 8; ++t) {
            float4 e = cbp[t];
            push4(e.x, __float_as_int(e.y), bs, bi);
            push4(e.z, __float_as_int(e.w), bs, bi);
        }
#pragma unroll
        for (int j = 0; j < 4; ++j) si[j] = bi[j];
        // s1: tiles 8..11
#pragma unroll
        for (int j = 0; j < 4; ++j) { bs[j] = 3.4e38f; bi[j] = 0x7fffffff; }
#pragma unroll
        for (int t = 8; t < 12; ++t) {
            float4 e = cbp[t];
            push4(e.x, __float_as_int(e.y), bs, bi);
            push4(e.z, __float_as_int(e.w), bs, bi);
        }
#pragma unroll
        for (int j = 0; j < 4; ++j) si[4 + j] = bi[j];
        // s2: tiles 12..13 (4 candidates total)
#pragma unroll
        for (int j = 0; j < 4; ++j) { bs[j] = 3.4e38f; bi[j] = 0x7fffffff; }
#pragma unroll
        for (int t = 12; t < 14; ++t) {
            float4 e = cbp[t];
            push4(e.x, __float_as_int(e.y), bs, bi);
            push4(e.z, __float_as_int(e.w), bs, bi);
        }
#pragma unroll
        for (int j = 0; j < 4; ++j) si[8 + j] = bi[j];
    }

    // exact fp32 dots for all 12 candidates
    float d[12];
#pragma unroll
    for (int k = 0; k < 12; ++k) {
        const float4* cp = (const float4*)(CB + (size_t)si[k] * DK) + lane * 2;
        float4 a = cp[0], b = cp[1];
        d[k] = xa.x * a.x + xa.y * a.y + xa.z * a.z + xa.w * a.w
             + xb.x * b.x + xb.y * b.y + xb.z * b.z + xb.w * b.w;
    }
#pragma unroll
    for (int off = 32; off; off >>= 1)
#pragma unroll
        for (int k = 0; k < 12; ++k) d[k] += __shfl_xor(d[k], off, 64);

    float sc[12];
#pragma unroll
    for (int k = 0; k < 12; ++k) sc[k] = norms[si[k]] - 2.f * d[k];

    int pick[3];
#pragma unroll
    for (int g = 0; g < 3; ++g) {
        float bv = sc[g * 4]; int bidx = si[g * 4];
#pragma unroll
        for (int k = 1; k < 4; ++k) {
            float v = sc[g * 4 + k]; int idx = si[g * 4 + k];
            if (v < bv || (v == bv && idx < bidx)) { bv = v; bidx = idx; }
        }
        pick[g] = bidx;
    }
    const int A = pick[0], B = pick[1], C = pick[2];

    // gather + write + loss
    const float4* pa = (const float4*)(CB + (size_t)A * DK) + lane * 2;
    const float4* pb = (const float4*)(CB + (size_t)B * DK) + lane * 2;
    const float4* pc = (const float4*)(CB + (size_t)C * DK) + lane * 2;
    float4* mo = (float4*)(main_out + (size_t)r * DK) + lane * 2;
    float4* so = (float4*)(sub_out + (size_t)r * DK) + lane * 2;
    float em = 0.f, es = 0.f;
#pragma unroll
    for (int i = 0; i < 2; ++i) {
        float4 xq = (i == 0) ? xa : xb;
        float4 cm = pa[i];
        float4 q1 = pb[i];
        float4 q2 = pc[i];
        float4 cs;
        cs.x = 0.5f * (q1.x + q2.x);
        cs.y = 0.5f * (q1.y + q2.y);
        cs.z = 0.5f * (q1.z + q2.z);
        cs.w = 0.5f * (q1.w + q2.w);
        mo[i] = cm;
        so[i] = cs;
        float t;
        t = cm.x - xq.x; em += t * t;
        t = cm.y - xq.y; em += t * t;
        t = cm.z - xq.z; em += t * t;
        t = cm.w - xq.w; em += t * t;
        t = cs.x - xq.x; es += t * t;
        t = cs.y - xq.y; es += t * t;
        t = cs.z - xq.z; es += t * t;
        t = cs.w - xq.w; es += t * t;
    }
#pragma unroll
    for (int off = 32; off; off >>= 1) {
        em += __shfl_down(em, off, 64);
        es += __shfl_down(es, off, 64);
    }
    __shared__ float sm[8];
    if (lane == 0) {
        sm[wv] = em; sm[4 + wv] = es;
        used[A] = 1;  // benign race: same value
    }
    __syncthreads();
    if (threadIdx.x == 0) {
        lossPart[blockIdx.x] = make_float2(sm[0] + sm[1] + sm[2] + sm[3],
                                           sm[4] + sm[5] + sm[6] + sm[7]);
    }
}

// ---------------------------------------------------------------------------
// Reduce 8192 loss partials + count used codes + write scalars + zero ms_k_i.
__global__ __launch_bounds__(256) void finalize_kernel(
    const int* __restrict__ used, const float2* __restrict__ lossPart,
    const int* __restrict__ training, float* __restrict__ out)
{
    int tid = threadIdx.x;
    int cnt = 0;
    for (int i = tid; i < 1024; i += 256) cnt += (used[i] != 0);
    float em = 0.f, es = 0.f;
    for (int i = tid; i < NBLK_RG; i += 256) {
        float2 p = lossPart[i];
        em += p.x; es += p.y;
    }
#pragma unroll
    for (int off = 32; off; off >>= 1) {
        cnt += __shfl_down(cnt, off, 64);
        em += __shfl_down(em, off, 64);
        es += __shfl_down(es, off, 64);
    }
    __shared__ int sc[4];
    __shared__ float se[4], ss[4];
    if ((tid & 63) == 0) { sc[tid >> 6] = cnt; se[tid >> 6] = em; ss[tid >> 6] = es; }
    __syncthreads();
    if (tid == 0) {
        int total = sc[0] + sc[1] + sc[2] + sc[3];
        float tl = 0.f;
        if (*training) {
            float l0 = se[0] + se[1] + se[2] + se[3];
            float l1 = ss[0] + ss[1] + ss[2] + ss[3];
            tl = 1.25f * (l0 + l1) * (1.0f / ((float)N_ROWS * (float)DK));
        }
        out[LOSS_OFF] = tl;
        out[UNIQ_OFF] = (float)total;
    }
    for (int i = tid; i < 8192; i += 256) out[MSK_OFF + i] = 0.f;
}

// ---------------------------------------------------------------------------
extern "C" void kernel_launch(void* const* d_in, const int* in_sizes, int n_in,
                              void* d_out, int out_size, void* d_ws, size_t ws_size,
                              hipStream_t stream) {
    const float* x = (const float*)d_in[0];
    const float* c = (const float*)d_in[1];
    const float* W1 = (const float*)d_in[2];
    const float* b1 = (const float*)d_in[3];
    const float* W2 = (const float*)d_in[4];
    const float* b2 = (const float*)d_in[5];
    const int* training = (const int*)d_in[6];
    float* out = (float*)d_out;

    // ws layout (all offsets 16B aligned); total ~46.5 MB
    char* p = (char*)d_ws;
    float* CB = (float*)p;          p += (size_t)NCB * DK * 4;        // 3,670,016
    _Float16* xh = (_Float16*)p;    p += (size_t)N_ROWS * DK * 2;     // 33,554,432
    _Float16* cbh = (_Float16*)p;   p += (size_t)NCB * DK * 2;        // 1,835,008
    float4* candbuf = (float4*)p;   p += (size_t)N_ROWS * NTILE * 16; // 7,340,032
    float* norms = (float*)p;       p += NCB * 4;                     // 7,168
    float2* lossPart = (float2*)p;  p += (size_t)NBLK_RG * 8;         // 65,536
    int* used = (int*)p;            p += 4096;

    init_kernel<<<dim3(4), dim3(256), 0, stream>>>(used);
    build_subcb<<<dim3(8, 112), dim3(256), 0, stream>>>(c, W1, b1, W2, b2, CB);
    row_norms<<<dim3(NCB), dim3(64), 0, stream>>>(CB, norms);
    cvt_f16<<<dim3(8192), dim3(256), 0, stream>>>(x, xh, N_ROWS * DK / 8);
    cvt_f16<<<dim3(448), dim3(256), 0, stream>>>(CB, cbh, NCB * DK / 8);
    gemm_topk<<<dim3(NTILE, 256), dim3(256), 0, stream>>>(xh, cbh, norms, candbuf);
    rescue_gather<<<dim3(NBLK_RG), dim3(256), 0, stream>>>(
        x, CB, norms, candbuf, out + MAIN_OFF, out + SUB_OFF, lossPart, used);
    finalize_kernel<<<dim3(1), dim3(256), 0, stream>>>(used, lossPart, training, out);
}

// Round 4
// 414.389 us; speedup vs baseline: 3.9931x; 1.1491x over previous
//
#include <hip/hip_runtime.h>
#include <cstdint>

typedef unsigned short ushort_t;
typedef unsigned int uint_t;
typedef _Float16 f16x8 __attribute__((ext_vector_type(8)));
typedef float f32x4 __attribute__((ext_vector_type(4)));

#define N_ROWS 32768
#define DK 512
#define NC_MAIN 1024
#define NCB 1792  // 1024 + 512 + 256
#define NTILE 14  // 1792 / 128
#define NBLK_RG 8192  // rescue_gather blocks (4 rows each)

// d_out layout (floats, concatenated reference outputs)
#define MAIN_OFF 0
#define SUB_OFF  16777216
#define LOSS_OFF 33554432
#define MSK_OFF  33554433
#define UNIQ_OFF 33562625

__device__ __forceinline__ uint_t umin_(uint_t a, uint_t b) { return a < b ? a : b; }
__device__ __forceinline__ uint_t umax_(uint_t a, uint_t b) { return a > b ? a : b; }

// ---------------------------------------------------------------------------
// Build combined codebook CB[1792][512] (fp32) AND its f16 copy cbh.
// rows 0..1023 copy of c; 1024..1535 = W1@c+b1; 1536..1791 = W2@c+b2.
__global__ __launch_bounds__(256) void build_subcb(
    const float* __restrict__ c, const float* __restrict__ W1,
    const float* __restrict__ b1, const float* __restrict__ W2,
    const float* __restrict__ b2, float* __restrict__ CB,
    _Float16* __restrict__ cbh)
{
    int tid = threadIdx.x;
    int tx = tid & 63, ty = tid >> 6;
    int col = blockIdx.x * 64 + tx;
    int row0 = blockIdx.y * 16 + ty * 4;
    if (row0 < 1024) {
#pragma unroll
        for (int r = 0; r < 4; ++r) {
            float v = c[(row0 + r) * DK + col];
            CB[(row0 + r) * DK + col] = v;
            cbh[(row0 + r) * DK + col] = (_Float16)v;
        }
    } else {
        int i0 = row0 - 1024;
        const float* W;
        const float* b;
        if (i0 < 512) { W = W1; b = b1; }
        else          { W = W2; b = b2; i0 -= 512; }
        float acc[4] = {0.f, 0.f, 0.f, 0.f};
#pragma unroll 8
        for (int j = 0; j < 1024; ++j) {
            float cv = c[j * DK + col];
#pragma unroll
            for (int r = 0; r < 4; ++r)
                acc[r] += W[(i0 + r) * 1024 + j] * cv;
        }
#pragma unroll
        for (int r = 0; r < 4; ++r) {
            float v = acc[r] + b[i0 + r];
            CB[(row0 + r) * DK + col] = v;
            cbh[(row0 + r) * DK + col] = (_Float16)v;
        }
    }
}

// ---------------------------------------------------------------------------
__global__ __launch_bounds__(64) void row_norms(const float* __restrict__ CB,
                                                float* __restrict__ norms) {
    int row = blockIdx.x;
    int lane = threadIdx.x;
    const float4* p = (const float4*)(CB + (size_t)row * DK);
    float s = 0.f;
#pragma unroll
    for (int i = lane; i < 128; i += 64) {
        float4 v = p[i];
        s += v.x * v.x + v.y * v.y + v.z * v.z + v.w * v.w;
    }
#pragma unroll
    for (int off = 32; off; off >>= 1) s += __shfl_down(s, off, 64);
    if (lane == 0) norms[row] = s;
}

// ---------------------------------------------------------------------------
// fp32 -> f16 (RN) for x, 8 elems/thread; also zeroes `used` (init fused).
__global__ __launch_bounds__(256) void cvt_x(const float* __restrict__ in,
                                             _Float16* __restrict__ out,
                                             int* __restrict__ used) {
    int i = blockIdx.x * 256 + threadIdx.x;
    if (i < 1024) used[i] = 0;
    const float4* p = (const float4*)in + (size_t)i * 2;
    float4 a = p[0], b = p[1];
    f16x8 o;
    o[0] = (_Float16)a.x; o[1] = (_Float16)a.y; o[2] = (_Float16)a.z; o[3] = (_Float16)a.w;
    o[4] = (_Float16)b.x; o[5] = (_Float16)b.y; o[6] = (_Float16)b.z; o[7] = (_Float16)b.w;
    *((f16x8*)out + i) = o;
}

// ---------------------------------------------------------------------------
__device__ __forceinline__ void async16(void* lds, const void* g) {
    __builtin_amdgcn_global_load_lds(
        (const __attribute__((address_space(1))) unsigned int*)(uintptr_t)g,
        (__attribute__((address_space(3))) unsigned int*)(uintptr_t)lds,
        16, 0, 0);
}

// ---------------------------------------------------------------------------
// MFMA f16 GEMM S = xh . cbh^T with per-(row, 128-col-tile) top-2 epilogue.
// Block: 256 thr = 4 waves (2x2), tile 128x128, BK=32, double-buffered LDS
// with one __syncthreads per K-iter (loads for iter k+1 issued right after
// the barrier, landing during compute of iter k).
// XCD swizzle: the 14 blocks sharing an A-strip get equal bid%8 -> same XCD
// L2 keeps the strip resident (A fetched from HBM ~once).
// Bank-conflict avoidance: XOR-permute which GLOBAL granule each lane
// fetches; LDS dest stays lane-linear (global_load_lds constraint).
// Candidate keys: sortable-u32 score bits (top 21) | global code idx (11).
__global__ __launch_bounds__(256) void gemm_topk(
    const _Float16* __restrict__ xh, const _Float16* __restrict__ cbh,
    const float* __restrict__ norms, uint2* __restrict__ candbuf)
{
    __shared__ __align__(16) ushort_t As[2][128 * 32];
    __shared__ __align__(16) ushort_t Bs[2][128 * 32];
    __shared__ uint2 cand[128][2];

    const int tid = threadIdx.x;
    const int lane = tid & 63;
    const int wid = tid >> 6;
    const int wy = wid >> 1, wx = wid & 1;
    const int lane15 = lane & 15, q = lane >> 4;

    // XCD-aware remap (launch order: blockIdx.x fastest)
    const int bid = blockIdx.y * NTILE + blockIdx.x;
    const int xcd = bid & 7;
    const int slot = bid >> 3;             // 0..447
    const int tileN = slot % NTILE;        // 0..13
    const int rowG = slot / NTILE;         // 0..31
    const int rowBase = (rowG * 8 + xcd) * 128;
    const int c0 = tileN * 128;

    // staging offsets: 512 granules (16B) per matrix per buffer, 2/thread
    size_t aoff[2], boff[2];
    int ldsoff[2];
#pragma unroll
    for (int i = 0; i < 2; ++i) {
        int gid = i * 256 + tid;     // 0..511
        int row = gid >> 2;          // 0..127
        int gp = gid & 3;
        int gsw = gp ^ (row & 3);
        aoff[i] = (size_t)(rowBase + row) * DK + gsw * 8;
        boff[i] = (size_t)(c0 + row) * DK + gsw * 8;
        ldsoff[i] = gid * 8;         // f16 elements
    }

    // fragment LDS row bases
    int rA[4], rB[4];
#pragma unroll
    for (int t = 0; t < 4; ++t) {
        rA[t] = wy * 64 + t * 16 + lane15;
        rB[t] = wx * 64 + t * 16 + lane15;
    }

    f32x4 acc[4][4];
#pragma unroll
    for (int mr = 0; mr < 4; ++mr)
#pragma unroll
        for (int nc = 0; nc < 4; ++nc) acc[mr][nc] = (f32x4)0.f;

    // preload chunk 0 into buffer 0
#pragma unroll
    for (int i = 0; i < 2; ++i) {
        async16(&As[0][ldsoff[i]], xh + aoff[i]);
        async16(&Bs[0][ldsoff[i]], cbh + boff[i]);
    }

#pragma unroll
    for (int it = 0; it < 16; ++it) {
        const int cur = it & 1;
        __syncthreads();   // drains this iter's loads; all waves done with other buf
        if (it < 15) {
            const int nxt = cur ^ 1;
            const int kk = (it + 1) * 32;
#pragma unroll
            for (int i = 0; i < 2; ++i) {
                async16(&As[nxt][ldsoff[i]], xh + aoff[i] + kk);
                async16(&Bs[nxt][ldsoff[i]], cbh + boff[i] + kk);
            }
        }
        f16x8 av[4], bv[4];
#pragma unroll
        for (int mr = 0; mr < 4; ++mr)
            av[mr] = *(const f16x8*)&As[cur][rA[mr] * 32 + (q ^ (rA[mr] & 3)) * 8];
#pragma unroll
        for (int nc = 0; nc < 4; ++nc)
            bv[nc] = *(const f16x8*)&Bs[cur][rB[nc] * 32 + (q ^ (rB[nc] & 3)) * 8];
#pragma unroll
        for (int mr = 0; mr < 4; ++mr)
#pragma unroll
            for (int nc = 0; nc < 4; ++nc)
                acc[mr][nc] = __builtin_amdgcn_mfma_f32_16x16x32_f16(
                    av[mr], bv[nc], acc[mr][nc], 0, 0, 0);
    }

    // ---------------- epilogue: per-row top-2 over the 128-col tile ----------
    float nrm[4];
    uint_t colGlob[4];
#pragma unroll
    for (int nc = 0; nc < 4; ++nc) {
        colGlob[nc] = (uint_t)(c0 + wx * 64 + nc * 16 + lane15);
        nrm[nc] = norms[colGlob[nc]];
    }

#pragma unroll
    for (int mr = 0; mr < 4; ++mr) {
#pragma unroll
        for (int r = 0; r < 4; ++r) {
            uint_t k[4];
#pragma unroll
            for (int nc = 0; nc < 4; ++nc) {
                float s = fmaf(-2.f, acc[mr][nc][r], nrm[nc]);
                uint_t b = __float_as_uint(s);
                uint_t u = b ^ ((uint_t)((int)b >> 31) | 0x80000000u);
                k[nc] = (u & 0xFFFFF800u) | colGlob[nc];
            }
            uint_t lo01 = umin_(k[0], k[1]), hi01 = umax_(k[0], k[1]);
            uint_t lo23 = umin_(k[2], k[3]), hi23 = umax_(k[2], k[3]);
            uint_t k1 = umin_(lo01, lo23);
            uint_t k2 = umin_(umin_(hi01, hi23), umax_(lo01, lo23));
#pragma unroll
            for (int m = 1; m <= 8; m <<= 1) {
                uint_t o1 = __shfl_xor(k1, m, 64);
                uint_t o2 = __shfl_xor(k2, m, 64);
                uint_t n1 = umin_(k1, o1);
                uint_t n2 = umin_(umax_(k1, o1), umin_(k2, o2));
                k1 = n1; k2 = n2;
            }
            if (lane15 == 0) {
                int rloc = wy * 64 + mr * 16 + q * 4 + r;
                cand[rloc][wx] = make_uint2(k1, k2);
            }
        }
    }
    __syncthreads();
    if (tid < 128) {
        uint2 a = cand[tid][0], b = cand[tid][1];
        uint_t k1 = umin_(a.x, b.x);
        uint_t k2 = umin_(umax_(a.x, b.x), umin_(a.y, b.y));
        candbuf[(size_t)(rowBase + tid) * NTILE + tileN] = make_uint2(k1, k2);
    }
}

// ---------------------------------------------------------------------------
// Per x-row: merge tile candidate keys per segment (top-4, pure u32 min/max on
// wave-uniform values), rescore exactly in fp32, pick argmin (tie -> lowest
// idx; idx lives in key low bits so key order matches), gather rows, write
// outputs, per-block loss partials, mark used. One wave per row.
__device__ __forceinline__ void push4u(uint_t v, uint_t* bs) {
#pragma unroll
    for (int j = 0; j < 4; ++j) {
        uint_t lo = umin_(v, bs[j]);
        uint_t hi = umax_(v, bs[j]);
        bs[j] = lo; v = hi;
    }
}

__global__ __launch_bounds__(256) void rescue_gather(
    const float* __restrict__ x, const float* __restrict__ CB,
    const float* __restrict__ norms, const uint2* __restrict__ candbuf,
    float* __restrict__ main_out, float* __restrict__ sub_out,
    float2* __restrict__ lossPart, int* __restrict__ used)
{
    const int lane = threadIdx.x & 63;
    const int wv = threadIdx.x >> 6;
    const int r = blockIdx.x * 4 + wv;

    const float4* xp = (const float4*)(x + (size_t)r * DK) + lane * 2;
    float4 xa = xp[0], xb = xp[1];

    const uint2* cbp = candbuf + (size_t)r * NTILE;

    int si[12];
    {
        uint_t bs[4];
        // main: tiles 0..7
#pragma unroll
        for (int j = 0; j < 4; ++j) bs[j] = 0xFFFFFFFFu;
#pragma unroll
        for (int t = 0; t < 8; ++t) {
            uint2 e = cbp[t];
            push4u(__builtin_amdgcn_readfirstlane(e.x), bs);
            push4u(__builtin_amdgcn_readfirstlane(e.y), bs);
        }
#pragma unroll
        for (int j = 0; j < 4; ++j) si[j] = (int)(bs[j] & 2047u);
        // s1: tiles 8..11
#pragma unroll
        for (int j = 0; j < 4; ++j) bs[j] = 0xFFFFFFFFu;
#pragma unroll
        for (int t = 8; t < 12; ++t) {
            uint2 e = cbp[t];
            push4u(__builtin_amdgcn_readfirstlane(e.x), bs);
            push4u(__builtin_amdgcn_readfirstlane(e.y), bs);
        }
#pragma unroll
        for (int j = 0; j < 4; ++j) si[4 + j] = (int)(bs[j] & 2047u);
        // s2: tiles 12..13 (exactly 4 candidates)
#pragma unroll
        for (int j = 0; j < 4; ++j) bs[j] = 0xFFFFFFFFu;
#pragma unroll
        for (int t = 12; t < 14; ++t) {
            uint2 e = cbp[t];
            push4u(__builtin_amdgcn_readfirstlane(e.x), bs);
            push4u(__builtin_amdgcn_readfirstlane(e.y), bs);
        }
#pragma unroll
        for (int j = 0; j < 4; ++j) si[8 + j] = (int)(bs[j] & 2047u);
    }

    // exact fp32 dots for all 12 candidates
    float d[12];
#pragma unroll
    for (int k = 0; k < 12; ++k) {
        const float4* cp = (const float4*)(CB + (size_t)si[k] * DK) + lane * 2;
        float4 a = cp[0], b = cp[1];
        d[k] = xa.x * a.x + xa.y * a.y + xa.z * a.z + xa.w * a.w
             + xb.x * b.x + xb.y * b.y + xb.z * b.z + xb.w * b.w;
    }
#pragma unroll
    for (int off = 32; off; off >>= 1)
#pragma unroll
        for (int k = 0; k < 12; ++k) d[k] += __shfl_xor(d[k], off, 64);

    float sc[12];
#pragma unroll
    for (int k = 0; k < 12; ++k) sc[k] = norms[si[k]] - 2.f * d[k];

    int pick[3];
#pragma unroll
    for (int g = 0; g < 3; ++g) {
        float bv = sc[g * 4]; int bidx = si[g * 4];
#pragma unroll
        for (int k = 1; k < 4; ++k) {
            float v = sc[g * 4 + k]; int idx = si[g * 4 + k];
            if (v < bv || (v == bv && idx < bidx)) { bv = v; bidx = idx; }
        }
        pick[g] = bidx;
    }
    const int A = pick[0], B = pick[1], C = pick[2];

    // gather + write + loss
    const float4* pa = (const float4*)(CB + (size_t)A * DK) + lane * 2;
    const float4* pb = (const float4*)(CB + (size_t)B * DK) + lane * 2;
    const float4* pc = (const float4*)(CB + (size_t)C * DK) + lane * 2;
    float4* mo = (float4*)(main_out + (size_t)r * DK) + lane * 2;
    float4* so = (float4*)(sub_out + (size_t)r * DK) + lane * 2;
    float em = 0.f, es = 0.f;
#pragma unroll
    for (int i = 0; i < 2; ++i) {
        float4 xq = (i == 0) ? xa : xb;
        float4 cm = pa[i];
        float4 q1 = pb[i];
        float4 q2 = pc[i];
        float4 cs;
        cs.x = 0.5f * (q1.x + q2.x);
        cs.y = 0.5f * (q1.y + q2.y);
        cs.z = 0.5f * (q1.z + q2.z);
        cs.w = 0.5f * (q1.w + q2.w);
        mo[i] = cm;
        so[i] = cs;
        float t;
        t = cm.x - xq.x; em += t * t;
        t = cm.y - xq.y; em += t * t;
        t = cm.z - xq.z; em += t * t;
        t = cm.w - xq.w; em += t * t;
        t = cs.x - xq.x; es += t * t;
        t = cs.y - xq.y; es += t * t;
        t = cs.z - xq.z; es += t * t;
        t = cs.w - xq.w; es += t * t;
    }
#pragma unroll
    for (int off = 32; off; off >>= 1) {
        em += __shfl_down(em, off, 64);
        es += __shfl_down(es, off, 64);
    }
    __shared__ float sm[8];
    if (lane == 0) {
        sm[wv] = em; sm[4 + wv] = es;
        used[A] = 1;  // benign race: same value
    }
    __syncthreads();
    if (threadIdx.x == 0) {
        lossPart[blockIdx.x] = make_float2(sm[0] + sm[1] + sm[2] + sm[3],
                                           sm[4] + sm[5] + sm[6] + sm[7]);
    }
}

// ---------------------------------------------------------------------------
// Reduce 8192 loss partials + count used codes + write scalars + zero ms_k_i.
__global__ __launch_bounds__(256) void finalize_kernel(
    const int* __restrict__ used, const float2* __restrict__ lossPart,
    const int* __restrict__ training, float* __restrict__ out)
{
    int tid = threadIdx.x;
    int cnt = 0;
    for (int i = tid; i < 1024; i += 256) cnt += (used[i] != 0);
    float em = 0.f, es = 0.f;
    for (int i = tid; i < NBLK_RG; i += 256) {
        float2 p = lossPart[i];
        em += p.x; es += p.y;
    }
#pragma unroll
    for (int off = 32; off; off >>= 1) {
        cnt += __shfl_down(cnt, off, 64);
        em += __shfl_down(em, off, 64);
        es += __shfl_down(es, off, 64);
    }
    __shared__ int sc[4];
    __shared__ float se[4], ss[4];
    if ((tid & 63) == 0) { sc[tid >> 6] = cnt; se[tid >> 6] = em; ss[tid >> 6] = es; }
    __syncthreads();
    if (tid == 0) {
        int total = sc[0] + sc[1] + sc[2] + sc[3];
        float tl = 0.f;
        if (*training) {
            float l0 = se[0] + se[1] + se[2] + se[3];
            float l1 = ss[0] + ss[1] + ss[2] + ss[3];
            tl = 1.25f * (l0 + l1) * (1.0f / ((float)N_ROWS * (float)DK));
        }
        out[LOSS_OFF] = tl;
        out[UNIQ_OFF] = (float)total;
    }
    for (int i = tid; i < 8192; i += 256) out[MSK_OFF + i] = 0.f;
}

// ---------------------------------------------------------------------------
extern "C" void kernel_launch(void* const* d_in, const int* in_sizes, int n_in,
                              void* d_out, int out_size, void* d_ws, size_t ws_size,
                              hipStream_t stream) {
    const float* x = (const float*)d_in[0];
    const float* c = (const float*)d_in[1];
    const float* W1 = (const float*)d_in[2];
    const float* b1 = (const float*)d_in[3];
    const float* W2 = (const float*)d_in[4];
    const float* b2 = (const float*)d_in[5];
    const int* training = (const int*)d_in[6];
    float* out = (float*)d_out;

    // ws layout (all offsets 16B aligned); total ~43 MB
    char* p = (char*)d_ws;
    float* CB = (float*)p;          p += (size_t)NCB * DK * 4;       // 3,670,016
    _Float16* xh = (_Float16*)p;    p += (size_t)N_ROWS * DK * 2;    // 33,554,432
    _Float16* cbh = (_Float16*)p;   p += (size_t)NCB * DK * 2;       // 1,835,008
    uint2* candbuf = (uint2*)p;     p += (size_t)N_ROWS * NTILE * 8; // 3,670,016
    float* norms = (float*)p;       p += NCB * 4;                    // 7,168
    float2* lossPart = (float2*)p;  p += (size_t)NBLK_RG * 8;        // 65,536
    int* used = (int*)p;            p += 4096;

    build_subcb<<<dim3(8, 112), dim3(256), 0, stream>>>(c, W1, b1, W2, b2, CB, cbh);
    row_norms<<<dim3(NCB), dim3(64), 0, stream>>>(CB, norms);
    cvt_x<<<dim3(8192), dim3(256), 0, stream>>>(x, xh, used);
    gemm_topk<<<dim3(NTILE, 256), dim3(256), 0, stream>>>(xh, cbh, norms, candbuf);
    rescue_gather<<<dim3(NBLK_RG), dim3(256), 0, stream>>>(
        x, CB, norms, candbuf, out + MAIN_OFF, out + SUB_OFF, lossPart, used);
    finalize_kernel<<<dim3(1), dim3(256), 0, stream>>>(used, lossPart, training, out);
}